// Round 3
// baseline (237.934 us; speedup 1.0000x reference)
//
#include <hip/hip_runtime.h>
#include <hip/hip_cooperative_groups.h>
#include <stdint.h>

// R14: fuse k01+k2+k34 into ONE cooperative launch (grid 256 = 1 block/CU,
// guaranteed co-resident; 2x grid.sync() replaces 2 kernel boundaries).
// - Phase A builds the per-(b,hc) sparse-table slab DIRECTLY in swizzled LDS
//   (48 KB, retained through phase C -> k34's 12.6 MB global table re-read
//   and re-staging are gone) while streaming levels 1..6 to global (16B
//   stores) for phase B, which needs cross-block h access.
// - Phase B = R12/R13 k2 MFMA pipeline, unchanged, in a unioned LDS region
//   (total static LDS 48 + 65.5 = 113.5 KiB < 160 KiB).
// - Phase C = R13 k34 gather against the retained slab.
// - __threadfence() (device-scope, cross-XCD L2 wb/inv) around each
//   grid.sync(); falls back to the known-good 3-kernel path if the
//   cooperative launch is rejected.

namespace cg = cooperative_groups;

typedef unsigned short u16;
typedef unsigned int u32;

#define B_    32
#define S_    64
#define H_    512
#define ATT_  128
#define NWIN  2016
#define NLEV  7
#define TLEV  6   // stored levels: 1..6

typedef __bf16 bf16x8 __attribute__((ext_vector_type(8)));
typedef float  f32x4  __attribute__((ext_vector_type(4)));

__device__ __forceinline__ float asf(u32 i) {
  union { u32 i; float f; } v; v.i = i; return v.f;
}
__device__ __forceinline__ u32 asu(float f) {
  union { float f; u32 i; } v; v.f = f; return v.i;
}
__device__ __forceinline__ float bf2f(u16 u) { return asf(((u32)u) << 16); }
__device__ __forceinline__ u16 f2bf(float f) {
  u32 i = asu(f);
  i += 0x7fffu + ((i >> 16) & 1u);   // round-to-nearest-even
  return (u16)(i >> 16);
}
// Exact bf16x2 max: halves viewed as f32 (low mantissa zero) -> v_max_f32
// exact; repack high halves.
__device__ __forceinline__ u32 bfmax2(u32 a, u32 b) {
  float a0 = asf(a << 16), a1 = asf(a & 0xffff0000u);
  float b0 = asf(b << 16), b1 = asf(b & 0xffff0000u);
  u32 m0 = asu(fmaxf(a0, b0)), m1 = asu(fmaxf(a1, b1));
  return (m1 & 0xffff0000u) | (m0 >> 16);
}
__device__ __forceinline__ uint4 bfmax8(uint4 a, uint4 b) {
  uint4 m;
  m.x = bfmax2(a.x, b.x); m.y = bfmax2(a.y, b.y);
  m.z = bfmax2(a.z, b.z); m.w = bfmax2(a.w, b.w);
  return m;
}
__device__ __forceinline__ bf16x8 as_bf16x8(uint4 v) {
  union { uint4 u; bf16x8 h; } c; c.u = v; return c.h;
}

// ========================= fused cooperative kernel =========================
// LDS map: Tslab [0,49152) persistent A->C (levels 1..6, 64-col slice,
// 16B-chunk XOR swizzle (c ^ (row&7))).  auxraw (67072 B) unioned:
//   phase A: buf0 (level-0 slab, unswizzled)          [0, 8192)
//   phase B: Ts[2][8192]u16 [0,32768) | Bs [32768,65536) | widx [65536,66048)
//            b1s [66048,66560) | w2s [66560,67072)
//   phase C: attn_l f32 [0,8064) | widx [8064,12096) | red [12096,13120)
//            wredM [13120,13136) | wredS [13136,13152)
__launch_bounds__(256, 1)
__global__ void fused_all(const float* __restrict__ lstm, const float* __restrict__ W1,
                          const float* __restrict__ b1, const float* __restrict__ w2,
                          u16* __restrict__ table, u16* __restrict__ w1t,
                          u16* __restrict__ widx, float* __restrict__ scores,
                          float* __restrict__ out) {
  __shared__ __align__(16) u16 Tslab[TLEV * 64 * 64];   // 48 KB
  __shared__ __align__(16) char auxraw[67072];
  const int bid = blockIdx.x, tid = threadIdx.x;
  cg::grid_group grid = cg::this_grid();

  // ------------------------------ phase A -------------------------------
  {
    // folded: W1^T slice (1 elem/thread) + widx (blocks 0..7)
    {
      int idx = bid * 256 + tid;
      int n = idx >> 9, kq = idx & 511;
      w1t[idx] = f2bf(W1[kq * ATT_ + n]);
    }
    if (bid < 8) {
      int n = bid * 256 + tid;
      if (n < NWIN) {
        int w = 2, rem = n;
        while (rem >= 65 - w) { rem -= 65 - w; ++w; }
        int s = rem;
        int k = 31 - __clz(w);
        int e2 = s + w - (1 << k);
        widx[n] = (u16)(s | (e2 << 6) | (k << 12));
      }
    }

    int hc = bid & 7, bb = bid >> 3;
    const float* src = lstm + (size_t)bb * S_ * H_ + hc * 64;
    u16* tb = table + (size_t)bb * TLEV * S_ * H_ + hc * 64;
    u16* buf0 = (u16*)auxraw;   // level 0, unswizzled [64][64]

    for (int t = tid; t < 64 * 16; t += 256) {
      int r = t >> 4, c4 = t & 15;
      float4 f = *reinterpret_cast<const float4*>(src + r * H_ + c4 * 4);
      ushort4 u;
      u.x = f2bf(f.x); u.y = f2bf(f.y); u.z = f2bf(f.z); u.w = f2bf(f.w);
      *reinterpret_cast<ushort4*>(&buf0[r * 64 + c4 * 4]) = u;
    }
    __syncthreads();

    for (int k = 1; k < NLEV; ++k) {
      int half = 1 << (k - 1);
      u16* dstT = Tslab + (k - 1) * 4096;
      const u16* srcL = (k == 1) ? buf0 : (Tslab + (k - 2) * 4096);
      const int swz = (k != 1);
      u16* dst_g = tb + (size_t)(k - 1) * S_ * H_;
      for (int t = tid; t < 64 * 8; t += 256) {   // 64 rows x 8 16B-chunks
        int r = t >> 3, c = t & 7;
        int r2 = r + half; if (r2 > 63) r2 = 63;  // replicated tail, never read
        int ca = swz ? (c ^ (r  & 7)) : c;
        int cb = swz ? (c ^ (r2 & 7)) : c;
        uint4 a  = *reinterpret_cast<const uint4*>(&srcL[r  * 64 + ca * 8]);
        uint4 bq = *reinterpret_cast<const uint4*>(&srcL[r2 * 64 + cb * 8]);
        uint4 m = bfmax8(a, bq);
        *reinterpret_cast<uint4*>(&dstT[r * 64 + ((c ^ (r & 7)) * 8)]) = m;
        *reinterpret_cast<uint4*>(dst_g + r * H_ + c * 8) = m;
      }
      __syncthreads();
    }
  }

  __threadfence();
  grid.sync();
  __threadfence();

  // ------------------------------ phase B -------------------------------
  {
    const int bb = bid >> 3, mt = bid & 7;
    u16* TsB = (u16*)auxraw;               // [2][8192]
    u16* BsB = (u16*)(auxraw + 32768);     // [2][8192]
    u16* widx_l = (u16*)(auxraw + 65536);  // [256]
    float* b1s = (float*)(auxraw + 66048); // [128]
    float* w2s = (float*)(auxraw + 66560); // [128]

    {
      int n = mt * 256 + tid; if (n > NWIN - 1) n = NWIN - 1;  // pad-clamp
      widx_l[tid] = widx[n];
    }
    if (tid < 128) { b1s[tid] = b1[tid]; w2s[tid] = w2[tid]; }
    __syncthreads();

    const int lv_lo = widx_l[0] >> 12;   // tile's lowest level (>=1)
    const u16* tb = table + (size_t)bb * TLEV * S_ * H_ + (size_t)(lv_lo - 1) * S_ * H_;

    // DMA source pointers, pre-swizzled (m173): LDS dst LINEAR in lane,
    // the XOR involution applied to the GLOBAL source chunk index + reads.
    const u16* gT[4]; const u16* gB[4]; int sl[4];
#pragma unroll
    for (int p = 0; p < 4; ++p) {
      int slot = p * 256 + tid;
      int r = slot >> 3, c = slot & 7;
      int csw = (c ^ (r & 7)) * 8;
      gT[p] = tb  + r * H_ + csw;
      gB[p] = w1t + r * H_ + csw;
      sl[p] = slot * 8;                 // linear LDS element offset
    }

#define DMA(KC, BSEL) do {                                                     \
    int ko_ = (KC) * 64;                                                       \
    _Pragma("unroll")                                                          \
    for (int p_ = 0; p_ < 4; ++p_) {                                           \
      __builtin_amdgcn_global_load_lds(                                        \
          (const __attribute__((address_space(1))) void*)(gT[p_] + ko_),       \
          (__attribute__((address_space(3))) void*)(TsB + (BSEL) * 8192 + sl[p_]), \
          16, 0, 0);                                                           \
      __builtin_amdgcn_global_load_lds(                                        \
          (const __attribute__((address_space(1))) void*)(gB[p_] + ko_),       \
          (__attribute__((address_space(3))) void*)(BsB + (BSEL) * 8192 + sl[p_]), \
          16, 0, 0);                                                           \
    }                                                                          \
  } while (0)

    int wid = tid >> 6, lane = tid & 63;
    int lrow = lane & 15, quad = lane >> 4;

    int aoff[4][2][2];
#pragma unroll
    for (int mi = 0; mi < 4; ++mi) {
      int pk = widx_l[wid * 64 + mi * 16 + lrow];
      int s = pk & 63, e2 = (pk >> 6) & 63, lv = (pk >> 12) - lv_lo;  // 0 or 1
      int rs = lv * 64 + s, re = lv * 64 + e2;
#pragma unroll
      for (int k2i = 0; k2i < 2; ++k2i) {
        int c = quad + k2i * 4;
        aoff[mi][k2i][0] = rs * 64 + ((c ^ (rs & 7)) * 8);
        aoff[mi][k2i][1] = re * 64 + ((c ^ (re & 7)) * 8);
      }
    }
    int boff[8][2];
#pragma unroll
    for (int j = 0; j < 8; ++j) {
      int n = j * 16 + lrow;
#pragma unroll
      for (int k2i = 0; k2i < 2; ++k2i) {
        int c = quad + k2i * 4;
        boff[j][k2i] = n * 64 + ((c ^ (n & 7)) * 8);
      }
    }

    f32x4 acc[4][8];
#pragma unroll
    for (int mi = 0; mi < 4; ++mi)
#pragma unroll
      for (int j = 0; j < 8; ++j) acc[mi][j] = (f32x4){0.f, 0.f, 0.f, 0.f};

    DMA(0, 0);

    for (int kc = 0; kc < 8; ++kc) {
      // Implicit vmcnt(0) drains exactly this chunk's 8 DMA loads (issued one
      // full compute-chunk ago); barrier publishes buf[kc&1] to all waves.
      __syncthreads();
      if (kc < 7) DMA(kc + 1, (kc + 1) & 1);
      const u16* Tc = TsB + (kc & 1) * 8192;
      const u16* Bc = BsB + (kc & 1) * 8192;
#pragma unroll
      for (int k2i = 0; k2i < 2; ++k2i) {
        bf16x8 bfr[8];
#pragma unroll
        for (int j = 0; j < 8; ++j)
          bfr[j] = *reinterpret_cast<const bf16x8*>(&Bc[boff[j][k2i]]);
#pragma unroll
        for (int mi = 0; mi < 4; ++mi) {
          uint4 va = *reinterpret_cast<const uint4*>(&Tc[aoff[mi][k2i][0]]);
          uint4 vb = *reinterpret_cast<const uint4*>(&Tc[aoff[mi][k2i][1]]);
          bf16x8 af = as_bf16x8(bfmax8(va, vb));
#pragma unroll
          for (int j = 0; j < 8; ++j)
            acc[mi][j] = __builtin_amdgcn_mfma_f32_16x16x32_bf16(af, bfr[j], acc[mi][j], 0, 0, 0);
        }
      }
    }
#undef DMA

    // epilogue: score[m] = sum_n relu(hid+b1)*w2 (b2 softmax-invariant)
#pragma unroll
    for (int mi = 0; mi < 4; ++mi) {
#pragma unroll
      for (int r = 0; r < 4; ++r) {
        float p = 0.f;
#pragma unroll
        for (int j = 0; j < 8; ++j) {
          int n = j * 16 + lrow;
          float v = acc[mi][j][r] + b1s[n];
          p += (v > 0.f ? v : 0.f) * w2s[n];
        }
        p += __shfl_xor(p, 1, 16);
        p += __shfl_xor(p, 2, 16);
        p += __shfl_xor(p, 4, 16);
        p += __shfl_xor(p, 8, 16);
        if (lrow == 0) {
          int nw = mt * 256 + wid * 64 + mi * 16 + quad * 4 + r;
          if (nw < NWIN) scores[bb * NWIN + nw] = p;
        }
      }
    }
  }

  __threadfence();
  grid.sync();
  __threadfence();

  // ------------------------------ phase C -------------------------------
  {
    const int hc = bid & 7, bb = bid >> 3;   // same (b,hc) as phase A: Tslab
    float* attn_l = (float*)auxraw;          // [NWIN]
    u16*  widxC  = (u16*)(auxraw + 8064);    // [NWIN]
    float* red   = (float*)(auxraw + 12096); // [4][64]
    float* wredM = (float*)(auxraw + 13120);
    float* wredS = (float*)(auxraw + 13136);
    int h0 = hc * 64;
    int lane = tid & 63, wid = tid >> 6;

    for (int n = tid; n < NWIN; n += 256) widxC[n] = widx[n];

    float mx = -1e30f;
    for (int n = tid; n < NWIN; n += 256) {
      float v = scores[bb * NWIN + n];
      attn_l[n] = v;
      mx = fmaxf(mx, v);
    }
#pragma unroll
    for (int off = 32; off > 0; off >>= 1) mx = fmaxf(mx, __shfl_xor(mx, off, 64));
    if (lane == 0) wredM[wid] = mx;
    __syncthreads();   // also covers widxC / attn_l staging above
    mx = fmaxf(fmaxf(wredM[0], wredM[1]), fmaxf(wredM[2], wredM[3]));
    float sum = 0.f;
    for (int n = tid; n < NWIN; n += 256) {
      float e = __expf(attn_l[n] - mx);
      attn_l[n] = e;
      sum += e;
    }
#pragma unroll
    for (int off = 32; off > 0; off >>= 1) sum += __shfl_xor(sum, off, 64);
    if (lane == 0) wredS[wid] = sum;
    __syncthreads();
    float inv = 1.f / (wredS[0] + wredS[1] + wredS[2] + wredS[3]);

    // gather: 32 groups x 63 windows; thread (g, hq) accumulates 8 h-cols
    int hq = tid & 7, g = tid >> 3;
    float acc[8];
#pragma unroll
    for (int j = 0; j < 8; ++j) acc[j] = 0.f;
    for (int i = 0; i < 63; ++i) {
      int n = g * 63 + i;
      int pk = widxC[n];
      float a = attn_l[n];
      int s = pk & 63, e2 = (pk >> 6) & 63, lv = pk >> 12;
      int rs = (lv - 1) * 64 + s, re = (lv - 1) * 64 + e2;
      uint4 va = *reinterpret_cast<const uint4*>(&Tslab[rs * 64 + ((hq ^ (rs & 7)) * 8)]);
      uint4 vb = *reinterpret_cast<const uint4*>(&Tslab[re * 64 + ((hq ^ (re & 7)) * 8)]);
      u32 ua, ub;
#define ACC2(UA, UB, J0) do {                                            \
      float xa0 = asf((UA) << 16), xa1 = asf((UA) & 0xffff0000u);        \
      float xb0 = asf((UB) << 16), xb1 = asf((UB) & 0xffff0000u);        \
      acc[(J0)]     = fmaf(a, fmaxf(xa0, xb0), acc[(J0)]);               \
      acc[(J0) + 1] = fmaf(a, fmaxf(xa1, xb1), acc[(J0) + 1]);           \
    } while (0)
      ua = va.x; ub = vb.x; ACC2(ua, ub, 0);
      ua = va.y; ub = vb.y; ACC2(ua, ub, 2);
      ua = va.z; ub = vb.z; ACC2(ua, ub, 4);
      ua = va.w; ub = vb.w; ACC2(ua, ub, 6);
#undef ACC2
    }

#pragma unroll
    for (int j = 0; j < 8; ++j) {
      acc[j] += __shfl_xor(acc[j], 8, 64);
      acc[j] += __shfl_xor(acc[j], 16, 64);
      acc[j] += __shfl_xor(acc[j], 32, 64);
    }
    if (lane < 8) {
#pragma unroll
      for (int j = 0; j < 8; ++j) red[wid * 64 + hq * 8 + j] = acc[j];
    }
    __syncthreads();
    if (tid < 64) {
      float s2 = red[0 * 64 + tid] + red[1 * 64 + tid] + red[2 * 64 + tid] + red[3 * 64 + tid];
      out[bb * H_ + h0 + tid] = s2 * inv;
    }
  }
}

// =================== fallback path: R13 3-kernel pipeline ===================
__launch_bounds__(256)
__global__ void k01_init(const float* __restrict__ lstm, const float* __restrict__ W1,
                         u16* __restrict__ table, u16* __restrict__ w1t,
                         u16* __restrict__ widx) {
  int bid = blockIdx.x, tid = threadIdx.x;
  __shared__ u16 bufA[64 * 64], bufB[64 * 64];
  {
    int idx = bid * 256 + tid;
    int n = idx >> 9, kq = idx & 511;
    w1t[idx] = f2bf(W1[kq * ATT_ + n]);
  }
  if (bid < 8) {
    int n = bid * 256 + tid;
    if (n < NWIN) {
      int w = 2, rem = n;
      while (rem >= 65 - w) { rem -= 65 - w; ++w; }
      int s = rem;
      int k = 31 - __clz(w);
      int e2 = s + w - (1 << k);
      widx[n] = (u16)(s | (e2 << 6) | (k << 12));
    }
  }
  int hc = bid & 7, b = bid >> 3;
  const float* src = lstm + (size_t)b * S_ * H_ + hc * 64;
  u16* tb = table + (size_t)b * TLEV * S_ * H_ + hc * 64;
  for (int t = tid; t < 64 * 16; t += 256) {
    int r = t >> 4, c4 = t & 15;
    float4 f = *reinterpret_cast<const float4*>(src + r * H_ + c4 * 4);
    ushort4 u;
    u.x = f2bf(f.x); u.y = f2bf(f.y); u.z = f2bf(f.z); u.w = f2bf(f.w);
    *reinterpret_cast<ushort4*>(&bufA[r * 64 + c4 * 4]) = u;
  }
  u16* pa = bufA; u16* pb = bufB;
  for (int k = 1; k < NLEV; ++k) {
    __syncthreads();
    int half = 1 << (k - 1);
    u16* dst_g = tb + (size_t)(k - 1) * S_ * H_;
    for (int t = tid; t < 64 * 16; t += 256) {
      int r = t >> 4, c4 = t & 15;
      int r2 = r + half; if (r2 > 63) r2 = 63;
      uint2 a  = *reinterpret_cast<const uint2*>(&pa[r  * 64 + c4 * 4]);
      uint2 bq = *reinterpret_cast<const uint2*>(&pa[r2 * 64 + c4 * 4]);
      uint2 m; m.x = bfmax2(a.x, bq.x); m.y = bfmax2(a.y, bq.y);
      *reinterpret_cast<uint2*>(&pb[r * 64 + c4 * 4]) = m;
      *reinterpret_cast<uint2*>(dst_g + r * H_ + c4 * 4) = m;
    }
    u16* tmp = pa; pa = pb; pb = tmp;
  }
}

__launch_bounds__(256, 1)
__global__ void k2_scores(const u16* __restrict__ table, const u16* __restrict__ w1t,
                          const float* __restrict__ b1, const float* __restrict__ w2,
                          const u16* __restrict__ widx, float* __restrict__ scores) {
  const int b = blockIdx.y, mt = blockIdx.x;
  __shared__ u16 Ts[2][128 * 64];
  __shared__ u16 Bs[2][128 * 64];
  __shared__ u16 widx_l[256];
  __shared__ float b1s[128], w2s[128];
  int tid = threadIdx.x;
  {
    int n = mt * 256 + tid; if (n > NWIN - 1) n = NWIN - 1;
    widx_l[tid] = widx[n];
  }
  if (tid < 128) { b1s[tid] = b1[tid]; w2s[tid] = w2[tid]; }
  __syncthreads();

  const int lv_lo = widx_l[0] >> 12;
  const u16* tb = table + (size_t)b * TLEV * S_ * H_ + (size_t)(lv_lo - 1) * S_ * H_;

  const u16* gT[4]; const u16* gB[4]; int sl[4];
#pragma unroll
  for (int p = 0; p < 4; ++p) {
    int slot = p * 256 + tid;
    int r = slot >> 3, c = slot & 7;
    int csw = (c ^ (r & 7)) * 8;
    gT[p] = tb  + r * H_ + csw;
    gB[p] = w1t + r * H_ + csw;
    sl[p] = slot * 8;
  }

#define DMA(KC, BSEL) do {                                                     \
    int ko_ = (KC) * 64;                                                       \
    _Pragma("unroll")                                                          \
    for (int p_ = 0; p_ < 4; ++p_) {                                           \
      __builtin_amdgcn_global_load_lds(                                        \
          (const __attribute__((address_space(1))) void*)(gT[p_] + ko_),       \
          (__attribute__((address_space(3))) void*)(&Ts[(BSEL)][sl[p_]]),      \
          16, 0, 0);                                                           \
      __builtin_amdgcn_global_load_lds(                                        \
          (const __attribute__((address_space(1))) void*)(gB[p_] + ko_),       \
          (__attribute__((address_space(3))) void*)(&Bs[(BSEL)][sl[p_]]),      \
          16, 0, 0);                                                           \
    }                                                                          \
  } while (0)

  int wid = tid >> 6, lane = tid & 63;
  int lrow = lane & 15, quad = lane >> 4;

  int aoff[4][2][2];
#pragma unroll
  for (int mi = 0; mi < 4; ++mi) {
    int pk = widx_l[wid * 64 + mi * 16 + lrow];
    int s = pk & 63, e2 = (pk >> 6) & 63, lv = (pk >> 12) - lv_lo;
    int rs = lv * 64 + s, re = lv * 64 + e2;
#pragma unroll
    for (int k2i = 0; k2i < 2; ++k2i) {
      int c = quad + k2i * 4;
      aoff[mi][k2i][0] = rs * 64 + ((c ^ (rs & 7)) * 8);
      aoff[mi][k2i][1] = re * 64 + ((c ^ (re & 7)) * 8);
    }
  }
  int boff[8][2];
#pragma unroll
  for (int j = 0; j < 8; ++j) {
    int n = j * 16 + lrow;
#pragma unroll
    for (int k2i = 0; k2i < 2; ++k2i) {
      int c = quad + k2i * 4;
      boff[j][k2i] = n * 64 + ((c ^ (n & 7)) * 8);
    }
  }

  f32x4 acc[4][8];
#pragma unroll
  for (int mi = 0; mi < 4; ++mi)
#pragma unroll
    for (int j = 0; j < 8; ++j) acc[mi][j] = (f32x4){0.f, 0.f, 0.f, 0.f};

  DMA(0, 0);

  for (int kc = 0; kc < 8; ++kc) {
    __syncthreads();
    if (kc < 7) DMA(kc + 1, (kc + 1) & 1);
    const u16* Tc = Ts[kc & 1];
    const u16* Bc = Bs[kc & 1];
#pragma unroll
    for (int k2i = 0; k2i < 2; ++k2i) {
      bf16x8 bfr[8];
#pragma unroll
      for (int j = 0; j < 8; ++j)
        bfr[j] = *reinterpret_cast<const bf16x8*>(&Bc[boff[j][k2i]]);
#pragma unroll
      for (int mi = 0; mi < 4; ++mi) {
        uint4 va = *reinterpret_cast<const uint4*>(&Tc[aoff[mi][k2i][0]]);
        uint4 vb = *reinterpret_cast<const uint4*>(&Tc[aoff[mi][k2i][1]]);
        bf16x8 af = as_bf16x8(bfmax8(va, vb));
#pragma unroll
        for (int j = 0; j < 8; ++j)
          acc[mi][j] = __builtin_amdgcn_mfma_f32_16x16x32_bf16(af, bfr[j], acc[mi][j], 0, 0, 0);
      }
    }
  }
#undef DMA

#pragma unroll
  for (int mi = 0; mi < 4; ++mi) {
#pragma unroll
    for (int r = 0; r < 4; ++r) {
      float p = 0.f;
#pragma unroll
      for (int j = 0; j < 8; ++j) {
        int n = j * 16 + lrow;
        float v = acc[mi][j][r] + b1s[n];
        p += (v > 0.f ? v : 0.f) * w2s[n];
      }
      p += __shfl_xor(p, 1, 16);
      p += __shfl_xor(p, 2, 16);
      p += __shfl_xor(p, 4, 16);
      p += __shfl_xor(p, 8, 16);
      if (lrow == 0) {
        int nw = mt * 256 + wid * 64 + mi * 16 + quad * 4 + r;
        if (nw < NWIN) scores[b * NWIN + nw] = p;
      }
    }
  }
}

__launch_bounds__(256)
__global__ void k34_out(const u16* __restrict__ table, const float* __restrict__ scores,
                        const u16* __restrict__ widx, float* __restrict__ out) {
  int hc = blockIdx.x, b = blockIdx.y, tid = threadIdx.x;
  __shared__ u16 Tl[TLEV * 64 * 64];
  __shared__ float attn_l[NWIN];
  __shared__ u16 widx_l[NWIN];
  __shared__ float red[4][64];
  __shared__ float wredM[4], wredS[4];
  const u16* tb = table + (size_t)b * TLEV * S_ * H_;
  int h0 = hc * 64;
  int lane = tid & 63, wid = tid >> 6;

  for (int t = tid; t < TLEV * 64 * 8; t += 256) {
    int row = t >> 3, c = t & 7;
    uint4 v = *reinterpret_cast<const uint4*>(tb + row * H_ + h0 + c * 8);
    *reinterpret_cast<uint4*>(&Tl[row * 64 + ((c ^ (row & 7)) * 8)]) = v;
  }
  for (int n = tid; n < NWIN; n += 256) widx_l[n] = widx[n];

  float mx = -1e30f;
  for (int n = tid; n < NWIN; n += 256) {
    float v = scores[b * NWIN + n];
    attn_l[n] = v;
    mx = fmaxf(mx, v);
  }
#pragma unroll
  for (int off = 32; off > 0; off >>= 1) mx = fmaxf(mx, __shfl_xor(mx, off, 64));
  if (lane == 0) wredM[wid] = mx;
  __syncthreads();
  mx = fmaxf(fmaxf(wredM[0], wredM[1]), fmaxf(wredM[2], wredM[3]));
  float sum = 0.f;
  for (int n = tid; n < NWIN; n += 256) {
    float e = __expf(attn_l[n] - mx);
    attn_l[n] = e;
    sum += e;
  }
#pragma unroll
  for (int off = 32; off > 0; off >>= 1) sum += __shfl_xor(sum, off, 64);
  if (lane == 0) wredS[wid] = sum;
  __syncthreads();
  float inv = 1.f / (wredS[0] + wredS[1] + wredS[2] + wredS[3]);

  int hq = tid & 7, g = tid >> 3;
  float acc[8];
#pragma unroll
  for (int j = 0; j < 8; ++j) acc[j] = 0.f;
  for (int i = 0; i < 63; ++i) {
    int n = g * 63 + i;
    int pk = widx_l[n];
    float a = attn_l[n];
    int s = pk & 63, e2 = (pk >> 6) & 63, lv = pk >> 12;
    int rs = (lv - 1) * 64 + s, re = (lv - 1) * 64 + e2;
    uint4 va = *reinterpret_cast<const uint4*>(&Tl[rs * 64 + ((hq ^ (rs & 7)) * 8)]);
    uint4 vb = *reinterpret_cast<const uint4*>(&Tl[re * 64 + ((hq ^ (re & 7)) * 8)]);
    u32 ua, ub;
#define ACC2(UA, UB, J0) do {                                            \
      float xa0 = asf((UA) << 16), xa1 = asf((UA) & 0xffff0000u);        \
      float xb0 = asf((UB) << 16), xb1 = asf((UB) & 0xffff0000u);        \
      acc[(J0)]     = fmaf(a, fmaxf(xa0, xb0), acc[(J0)]);               \
      acc[(J0) + 1] = fmaf(a, fmaxf(xa1, xb1), acc[(J0) + 1]);           \
    } while (0)
    ua = va.x; ub = vb.x; ACC2(ua, ub, 0);
    ua = va.y; ub = vb.y; ACC2(ua, ub, 2);
    ua = va.z; ub = vb.z; ACC2(ua, ub, 4);
    ua = va.w; ub = vb.w; ACC2(ua, ub, 6);
#undef ACC2
  }

#pragma unroll
  for (int j = 0; j < 8; ++j) {
    acc[j] += __shfl_xor(acc[j], 8, 64);
    acc[j] += __shfl_xor(acc[j], 16, 64);
    acc[j] += __shfl_xor(acc[j], 32, 64);
  }
  if (lane < 8) {
#pragma unroll
    for (int j = 0; j < 8; ++j) red[wid][hq * 8 + j] = acc[j];
  }
  __syncthreads();
  if (tid < 64) {
    float s2 = red[0][tid] + red[1][tid] + red[2][tid] + red[3][tid];
    out[b * H_ + h0 + tid] = s2 * inv;
  }
}

// ================================ launch ===================================
extern "C" void kernel_launch(void* const* d_in, const int* in_sizes, int n_in,
                              void* d_out, int out_size, void* d_ws, size_t ws_size,
                              hipStream_t stream) {
  const float* lstm = (const float*)d_in[0];
  const float* W1   = (const float*)d_in[1];
  const float* b1   = (const float*)d_in[2];
  const float* W2   = (const float*)d_in[3];
  // d_in[4] = b2: uniform shift ahead of softmax -> no output effect, unused.
  float* out = (float*)d_out;

  char* ws = (char*)d_ws;
  // ws layout: widx u16 [0,4096) | w1t bf16 [4096,135168)
  //            | table bf16 levels 1..6 (12.58 MB) | scores f32 (258048 B)
  u16*   widx   = (u16*)(ws + 0);
  u16*   w1t    = (u16*)(ws + 4096);
  u16*   table  = (u16*)(ws + 135168);
  float* scores = (float*)(ws + 12718080);

  void* kargs[] = { (void*)&lstm, (void*)&W1, (void*)&b1, (void*)&W2,
                    (void*)&table, (void*)&w1t, (void*)&widx,
                    (void*)&scores, (void*)&out };
  hipError_t st = hipLaunchCooperativeKernel((const void*)fused_all,
                                             dim3(256), dim3(256),
                                             kargs, 0, stream);
  if (st != hipSuccess) {
    (void)hipGetLastError();   // clear; fall back to the 3-kernel path
    k01_init <<<256, 256, 0, stream>>>(lstm, W1, table, w1t, widx);
    k2_scores<<<dim3(8, B_), 256, 0, stream>>>(table, w1t, b1, W2, widx, scores);
    k34_out  <<<dim3(8, B_), 256, 0, stream>>>(table, scores, widx, out);
  }
}

// Round 4
// 115.592 us; speedup vs baseline: 2.0584x; 2.0584x over previous
//
#include <hip/hip_runtime.h>
#include <stdint.h>

// R15 = exact revert to R13 (best verified: 116.4 us). R14's cooperative
// fusion was refuted: 2x grid.sync() + device fences on a 256-block grid
// cost ~160 us (spin across non-coherent XCD L2s, 1 block/CU pinned by the
// 113.5 KiB LDS union) -- two plain kernel boundaries are far cheaper than
// two grid-wide syncs on this chip. Timed region is ~100 us harness poison
// fills (74-77% HBM peak, their own roofline) + ~13-16 us of our kernels.

typedef unsigned short u16;
typedef unsigned int u32;

#define B_    32
#define S_    64
#define H_    512
#define ATT_  128
#define NWIN  2016
#define NLEV  7
#define TLEV  6   // stored levels: 1..6

typedef __bf16 bf16x8 __attribute__((ext_vector_type(8)));
typedef float  f32x4  __attribute__((ext_vector_type(4)));

__device__ __forceinline__ float asf(u32 i) {
  union { u32 i; float f; } v; v.i = i; return v.f;
}
__device__ __forceinline__ u32 asu(float f) {
  union { float f; u32 i; } v; v.f = f; return v.i;
}
__device__ __forceinline__ float bf2f(u16 u) { return asf(((u32)u) << 16); }
__device__ __forceinline__ u16 f2bf(float f) {
  u32 i = asu(f);
  i += 0x7fffu + ((i >> 16) & 1u);   // round-to-nearest-even
  return (u16)(i >> 16);
}
// Exact bf16x2 max: halves viewed as f32 (low mantissa zero) -> v_max_f32
// exact; repack high halves.
__device__ __forceinline__ u32 bfmax2(u32 a, u32 b) {
  float a0 = asf(a << 16), a1 = asf(a & 0xffff0000u);
  float b0 = asf(b << 16), b1 = asf(b & 0xffff0000u);
  u32 m0 = asu(fmaxf(a0, b0)), m1 = asu(fmaxf(a1, b1));
  return (m1 & 0xffff0000u) | (m0 >> 16);
}
__device__ __forceinline__ uint4 bfmax8(uint4 a, uint4 b) {
  uint4 m;
  m.x = bfmax2(a.x, b.x); m.y = bfmax2(a.y, b.y);
  m.z = bfmax2(a.z, b.z); m.w = bfmax2(a.w, b.w);
  return m;
}
__device__ __forceinline__ bf16x8 as_bf16x8(uint4 v) {
  union { uint4 u; bf16x8 h; } c; c.u = v; return c.h;
}

// ============ k01: sparse table build + widx + W1^T (one launch) ============
// grid 256: per-(hc,b) 64-column slab; additionally every block transposes a
// 256-element slice of W1^T and blocks 0..7 emit widx. No tail round.
__launch_bounds__(256)
__global__ void k01_init(const float* __restrict__ lstm, const float* __restrict__ W1,
                         u16* __restrict__ table, u16* __restrict__ w1t,
                         u16* __restrict__ widx) {
  int bid = blockIdx.x, tid = threadIdx.x;
  __shared__ u16 bufA[64 * 64], bufB[64 * 64];

  // folded tail work: W1^T slice (65536 elems / 256 blocks = 1 per thread)
  {
    int idx = bid * 256 + tid;
    int n = idx >> 9, kq = idx & 511;
    w1t[idx] = f2bf(W1[kq * ATT_ + n]);
  }
  if (bid < 8) {
    int n = bid * 256 + tid;
    if (n < NWIN) {
      int w = 2, rem = n;
      while (rem >= 65 - w) { rem -= 65 - w; ++w; }
      int s = rem;
      int k = 31 - __clz(w);
      int e2 = s + w - (1 << k);
      widx[n] = (u16)(s | (e2 << 6) | (k << 12));
    }
  }

  int hc = bid & 7, b = bid >> 3;
  const float* src = lstm + (size_t)b * S_ * H_ + hc * 64;
  u16* tb = table + (size_t)b * TLEV * S_ * H_ + hc * 64;
  for (int t = tid; t < 64 * 16; t += 256) {
    int r = t >> 4, c4 = t & 15;
    float4 f = *reinterpret_cast<const float4*>(src + r * H_ + c4 * 4);
    ushort4 u;
    u.x = f2bf(f.x); u.y = f2bf(f.y); u.z = f2bf(f.z); u.w = f2bf(f.w);
    *reinterpret_cast<ushort4*>(&bufA[r * 64 + c4 * 4]) = u;
  }
  u16* pa = bufA; u16* pb = bufB;
  for (int k = 1; k < NLEV; ++k) {
    __syncthreads();
    int half = 1 << (k - 1);
    u16* dst_g = tb + (size_t)(k - 1) * S_ * H_;
    for (int t = tid; t < 64 * 16; t += 256) {
      int r = t >> 4, c4 = t & 15;
      int r2 = r + half; if (r2 > 63) r2 = 63;  // replicated tail, never read
      uint2 a  = *reinterpret_cast<const uint2*>(&pa[r  * 64 + c4 * 4]);
      uint2 bq = *reinterpret_cast<const uint2*>(&pa[r2 * 64 + c4 * 4]);
      uint2 m; m.x = bfmax2(a.x, bq.x); m.y = bfmax2(a.y, bq.y);
      *reinterpret_cast<uint2*>(&pb[r * 64 + c4 * 4]) = m;
      *reinterpret_cast<uint2*>(dst_g + r * H_ + c4 * 4) = m;
    }
    u16* tmp = pa; pa = pb; pb = tmp;
  }
}

// ====== k2: pooled @ W1 (MFMA bf16) + bias + relu + @W2 -> scores ==========
// grid (8, 32), 256 thr. Tile: 256 windows x 128 att, K=512 in 8 chunks of
// 64. Wave grid 4x1 in M, m=4 frags x j=8 frags per wave (acc 128 VGPR).
// Double-buffered Ts/Bs staged by global_load_lds DMA; one barrier/chunk.
__launch_bounds__(256, 1)
__global__ void k2_scores(const u16* __restrict__ table, const u16* __restrict__ w1t,
                          const float* __restrict__ b1, const float* __restrict__ w2,
                          const u16* __restrict__ widx, float* __restrict__ scores) {
  const int b = blockIdx.y, mt = blockIdx.x;
  __shared__ u16 Ts[2][128 * 64];   // 2 x (two level slabs, 64-K chunk), 32 KB
  __shared__ u16 Bs[2][128 * 64];   // 2 x (W1^T 128-att x 64-K chunk), 32 KB
  __shared__ u16 widx_l[256];
  __shared__ float b1s[128], w2s[128];
  int tid = threadIdx.x;
  {
    int n = mt * 256 + tid; if (n > NWIN - 1) n = NWIN - 1;  // pad-clamp
    widx_l[tid] = widx[n];
  }
  if (tid < 128) { b1s[tid] = b1[tid]; w2s[tid] = w2[tid]; }
  __syncthreads();

  const int lv_lo = widx_l[0] >> 12;   // tile's lowest level (>=1); max lv_lo+1
  const u16* tb = table + (size_t)b * TLEV * S_ * H_ + (size_t)(lv_lo - 1) * S_ * H_;

  // DMA source pointers, pre-swizzled (m173): pass p covers slot = p*256+tid,
  // r = slot>>3 in 0..127, c = slot&7 (16B chunk). LDS dst is LINEAR in lane
  // (slot*16B = wave-uniform base + lane*16); the XOR involution is applied
  // to the GLOBAL source chunk index instead, and again on the read side.
  const u16* gT[4]; const u16* gB[4]; int sl[4];
#pragma unroll
  for (int p = 0; p < 4; ++p) {
    int slot = p * 256 + tid;
    int r = slot >> 3, c = slot & 7;
    int csw = (c ^ (r & 7)) * 8;
    gT[p] = tb  + r * H_ + csw;
    gB[p] = w1t + r * H_ + csw;
    sl[p] = slot * 8;                 // linear LDS element offset
  }

#define DMA(KC, BSEL) do {                                                     \
    int ko_ = (KC) * 64;                                                       \
    _Pragma("unroll")                                                          \
    for (int p_ = 0; p_ < 4; ++p_) {                                           \
      __builtin_amdgcn_global_load_lds(                                        \
          (const __attribute__((address_space(1))) void*)(gT[p_] + ko_),       \
          (__attribute__((address_space(3))) void*)(&Ts[(BSEL)][sl[p_]]),      \
          16, 0, 0);                                                           \
      __builtin_amdgcn_global_load_lds(                                        \
          (const __attribute__((address_space(1))) void*)(gB[p_] + ko_),       \
          (__attribute__((address_space(3))) void*)(&Bs[(BSEL)][sl[p_]]),      \
          16, 0, 0);                                                           \
    }                                                                          \
  } while (0)

  int wid = tid >> 6, lane = tid & 63;
  int lrow = lane & 15, quad = lane >> 4;

  // A-fragment LDS offsets: wave wid owns windows [wid*64, wid*64+64),
  // m-frag mi covers windows wid*64 + mi*16 + lrow; {s,e2} rows x k2i.
  int aoff[4][2][2];
#pragma unroll
  for (int mi = 0; mi < 4; ++mi) {
    int pk = widx_l[wid * 64 + mi * 16 + lrow];
    int s = pk & 63, e2 = (pk >> 6) & 63, lv = (pk >> 12) - lv_lo;  // 0 or 1
    int rs = lv * 64 + s, re = lv * 64 + e2;
#pragma unroll
    for (int k2i = 0; k2i < 2; ++k2i) {
      int c = quad + k2i * 4;
      aoff[mi][k2i][0] = rs * 64 + ((c ^ (rs & 7)) * 8);
      aoff[mi][k2i][1] = re * 64 + ((c ^ (re & 7)) * 8);
    }
  }
  // B-fragment LDS offsets: 8 att columns x 2 k-steps (constant per lane)
  int boff[8][2];
#pragma unroll
  for (int j = 0; j < 8; ++j) {
    int n = j * 16 + lrow;
#pragma unroll
    for (int k2i = 0; k2i < 2; ++k2i) {
      int c = quad + k2i * 4;
      boff[j][k2i] = n * 64 + ((c ^ (n & 7)) * 8);
    }
  }

  f32x4 acc[4][8];
#pragma unroll
  for (int mi = 0; mi < 4; ++mi)
#pragma unroll
    for (int j = 0; j < 8; ++j) acc[mi][j] = (f32x4){0.f, 0.f, 0.f, 0.f};

  DMA(0, 0);

  for (int kc = 0; kc < 8; ++kc) {
    // Implicit vmcnt(0) here drains exactly this chunk's 8 DMA loads (issued
    // one full compute-chunk ago); barrier publishes buf[kc&1] to all waves.
    __syncthreads();
    if (kc < 7) DMA(kc + 1, (kc + 1) & 1);
    const u16* Tc = Ts[kc & 1];
    const u16* Bc = Bs[kc & 1];
#pragma unroll
    for (int k2i = 0; k2i < 2; ++k2i) {
      bf16x8 bfr[8];
#pragma unroll
      for (int j = 0; j < 8; ++j)
        bfr[j] = *reinterpret_cast<const bf16x8*>(&Bc[boff[j][k2i]]);
#pragma unroll
      for (int mi = 0; mi < 4; ++mi) {
        uint4 va = *reinterpret_cast<const uint4*>(&Tc[aoff[mi][k2i][0]]);
        uint4 vb = *reinterpret_cast<const uint4*>(&Tc[aoff[mi][k2i][1]]);
        bf16x8 af = as_bf16x8(bfmax8(va, vb));
#pragma unroll
        for (int j = 0; j < 8; ++j)
          acc[mi][j] = __builtin_amdgcn_mfma_f32_16x16x32_bf16(af, bfr[j], acc[mi][j], 0, 0, 0);
      }
    }
  }
#undef DMA

  // epilogue: score[m] = sum_n relu(hid+b1)*w2 (b2 dropped: softmax-invariant)
#pragma unroll
  for (int mi = 0; mi < 4; ++mi) {
#pragma unroll
    for (int r = 0; r < 4; ++r) {
      float p = 0.f;
#pragma unroll
      for (int j = 0; j < 8; ++j) {
        int n = j * 16 + lrow;
        float v = acc[mi][j][r] + b1s[n];
        p += (v > 0.f ? v : 0.f) * w2s[n];
      }
      p += __shfl_xor(p, 1, 16);
      p += __shfl_xor(p, 2, 16);
      p += __shfl_xor(p, 4, 16);
      p += __shfl_xor(p, 8, 16);
      if (lrow == 0) {
        int nw = mt * 256 + wid * 64 + mi * 16 + quad * 4 + r;
        if (nw < NWIN) scores[b * NWIN + nw] = p;
      }
    }
  }
}

// ========= k34: per-block softmax (redundant) + attn-weighted sum ==========
// grid (8, 32), 256 thr; 64-wide h slice per block (1 block/CU). Tl is
// XOR-swizzled so the two range-max rows are read as single ds_read_b128s
// (row-major [384][64] bf16 rows all start at bank 0 unswizzled). Each
// thread owns group g = tid>>3 (63 windows) x 8 h-cols hq = tid&7; bf16
// unpacked to f32 inline (no repack) and FMA'd into acc[8].
__launch_bounds__(256)
__global__ void k34_out(const u16* __restrict__ table, const float* __restrict__ scores,
                        const u16* __restrict__ widx, float* __restrict__ out) {
  int hc = blockIdx.x, b = blockIdx.y, tid = threadIdx.x;
  __shared__ u16 Tl[TLEV * 64 * 64];    // 48 KB: levels 1..6, 64-col slice, swizzled
  __shared__ float attn_l[NWIN];        // 8 KB, unnormalized exp
  __shared__ u16 widx_l[NWIN];          // 4 KB
  __shared__ float red[4][64];
  __shared__ float wredM[4], wredS[4];
  const u16* tb = table + (size_t)b * TLEV * S_ * H_;   // levels 1..6
  int h0 = hc * 64;
  int lane = tid & 63, wid = tid >> 6;

  // stage Tl: 384 rows x 8 16B-chunks; swizzle chunk idx with row&7
  for (int t = tid; t < TLEV * 64 * 8; t += 256) {
    int row = t >> 3, c = t & 7;
    uint4 v = *reinterpret_cast<const uint4*>(tb + row * H_ + h0 + c * 8);
    *reinterpret_cast<uint4*>(&Tl[row * 64 + ((c ^ (row & 7)) * 8)]) = v;
  }
  for (int n = tid; n < NWIN; n += 256) widx_l[n] = widx[n];

  float mx = -1e30f;
  for (int n = tid; n < NWIN; n += 256) {
    float v = scores[b * NWIN + n];
    attn_l[n] = v;
    mx = fmaxf(mx, v);
  }
#pragma unroll
  for (int off = 32; off > 0; off >>= 1) mx = fmaxf(mx, __shfl_xor(mx, off, 64));
  if (lane == 0) wredM[wid] = mx;
  __syncthreads();   // also covers the Tl / widx_l / attn_l staging above
  mx = fmaxf(fmaxf(wredM[0], wredM[1]), fmaxf(wredM[2], wredM[3]));
  float sum = 0.f;
  for (int n = tid; n < NWIN; n += 256) {
    float e = __expf(attn_l[n] - mx);
    attn_l[n] = e;
    sum += e;
  }
#pragma unroll
  for (int off = 32; off > 0; off >>= 1) sum += __shfl_xor(sum, off, 64);
  if (lane == 0) wredS[wid] = sum;
  __syncthreads();
  float inv = 1.f / (wredS[0] + wredS[1] + wredS[2] + wredS[3]);

  // gather: 32 groups x 63 windows; thread (g, hq) accumulates 8 h-cols
  int hq = tid & 7, g = tid >> 3;
  float acc[8];
#pragma unroll
  for (int j = 0; j < 8; ++j) acc[j] = 0.f;
  for (int i = 0; i < 63; ++i) {
    int n = g * 63 + i;
    int pk = widx_l[n];
    float a = attn_l[n];
    int s = pk & 63, e2 = (pk >> 6) & 63, lv = pk >> 12;
    int rs = (lv - 1) * 64 + s, re = (lv - 1) * 64 + e2;
    uint4 va = *reinterpret_cast<const uint4*>(&Tl[rs * 64 + ((hq ^ (rs & 7)) * 8)]);
    uint4 vb = *reinterpret_cast<const uint4*>(&Tl[re * 64 + ((hq ^ (re & 7)) * 8)]);
    // unpack bf16 pairs to f32, max, fma (no repack needed)
    u32 ua, ub;
#define ACC2(UA, UB, J0) do {                                            \
      float xa0 = asf((UA) << 16), xa1 = asf((UA) & 0xffff0000u);        \
      float xb0 = asf((UB) << 16), xb1 = asf((UB) & 0xffff0000u);        \
      acc[(J0)]     = fmaf(a, fmaxf(xa0, xb0), acc[(J0)]);               \
      acc[(J0) + 1] = fmaf(a, fmaxf(xa1, xb1), acc[(J0) + 1]);           \
    } while (0)
    ua = va.x; ub = vb.x; ACC2(ua, ub, 0);
    ua = va.y; ub = vb.y; ACC2(ua, ub, 2);
    ua = va.z; ub = vb.z; ACC2(ua, ub, 4);
    ua = va.w; ub = vb.w; ACC2(ua, ub, 6);
#undef ACC2
  }

  // reduce over 32 groups: first over the 8 groups within each wave
  // (lane = (g&7)*8 + hq -> xor lane bits 3..5), then over 4 waves via LDS.
#pragma unroll
  for (int j = 0; j < 8; ++j) {
    acc[j] += __shfl_xor(acc[j], 8, 64);
    acc[j] += __shfl_xor(acc[j], 16, 64);
    acc[j] += __shfl_xor(acc[j], 32, 64);
  }
  if (lane < 8) {
#pragma unroll
    for (int j = 0; j < 8; ++j) red[wid][hq * 8 + j] = acc[j];
  }
  __syncthreads();
  if (tid < 64) {
    float s2 = red[0][tid] + red[1][tid] + red[2][tid] + red[3][tid];
    out[b * H_ + h0 + tid] = s2 * inv;
  }
}

// ================================ launch ===================================
extern "C" void kernel_launch(void* const* d_in, const int* in_sizes, int n_in,
                              void* d_out, int out_size, void* d_ws, size_t ws_size,
                              hipStream_t stream) {
  const float* lstm = (const float*)d_in[0];
  const float* W1   = (const float*)d_in[1];
  const float* b1   = (const float*)d_in[2];
  const float* W2   = (const float*)d_in[3];
  // d_in[4] = b2: uniform shift ahead of softmax -> no output effect, unused.
  float* out = (float*)d_out;

  char* ws = (char*)d_ws;
  // ws layout: widx u16 [0,4096) | w1t bf16 [4096,135168)
  //            | table bf16 levels 1..6 (12.58 MB) | scores f32 (258048 B)
  u16*   widx   = (u16*)(ws + 0);
  u16*   w1t    = (u16*)(ws + 4096);
  u16*   table  = (u16*)(ws + 135168);
  float* scores = (float*)(ws + 12718080);

  k01_init <<<256, 256, 0, stream>>>(lstm, W1, table, w1t, widx);
  k2_scores<<<dim3(8, B_), 256, 0, stream>>>(table, w1t, b1, W2, widx, scores);
  k34_out  <<<dim3(8, B_), 256, 0, stream>>>(table, scores, widx, out);
}